// Round 1
// baseline (237.367 us; speedup 1.0000x reference)
//
#include <hip/hip_runtime.h>

// SoftPool 2d: x(32,128,128,64) fp32, 2x2/stride2 windows.
// Per pixel: h = tanh(x @ We + be)  (64->128), logit = sigmoid(h @ Wr + br).
// Per window: softmax over 4 logits, out = sum_e w_e * x_e  (fp32 blend).
// One wave = 16 pixels = 4 windows; mfma_f32_16x16x32_bf16, N=128 (8 tiles), K=64 (2 steps).

typedef __attribute__((ext_vector_type(8))) short short8;    // 8 bf16 = 4 VGPRs
typedef __attribute__((ext_vector_type(4))) float floatx4;

#define B_   32
#define R_   128
#define C_   128
#define D_   64
#define H_   128
#define SR_  64
#define SC_  64
#define NW_  (B_ * SR_ * SC_)   // 131072 windows
#define NGRP_ (NW_ / 4)         // 32768 groups of 4 windows (one per wave-iter)
#define NBLK_ 2048
#define NWAVE_ (NBLK_ * 4)      // 8192 waves
#define L_   (NGRP_ / NWAVE_)   // 4 iters per wave
#define WTS_ 72                 // padded We^T row stride in shorts (bank-conflict break)

__device__ __forceinline__ unsigned short f2bf(float f) {
  union { float f; unsigned int u; } v; v.f = f;
  unsigned int u = v.u;
  u += 0x7fffu + ((u >> 16) & 1u);   // round-to-nearest-even
  return (unsigned short)(u >> 16);
}

__device__ __forceinline__ float fast_tanh(float x) {
  float e = __expf(2.0f * x);        // v_exp_f32 path
  return 1.0f - 2.0f / (e + 1.0f);   // exact limits at +-inf
}

__global__ __launch_bounds__(256, 2) void softpool_kernel(
    const float* __restrict__ x, const float* __restrict__ We,
    const float* __restrict__ be, const float* __restrict__ Wr,
    const float* __restrict__ br, float* __restrict__ out)
{
  // We^T in LDS as bf16: WeT[h][d], padded row stride 72
  __shared__ __attribute__((aligned(16))) unsigned short WeT[H_ * WTS_];

  const int tid = threadIdx.x;
  for (int idx = tid; idx < D_ * H_; idx += 256) {
    int d = idx >> 7;       // We is (64,128) row-major: idx = d*128 + h
    int h = idx & 127;
    WeT[h * WTS_ + d] = f2bf(We[idx]);
  }
  __syncthreads();

  const int lane = tid & 63;
  const int wv   = tid >> 6;
  const int c    = lane & 15;   // A row (pixel-in-tile) / C col / out channel group
  const int quad = lane >> 4;   // k-quad for A/B; window-in-group for C/out

  // Preload B fragments to registers: 8 N-tiles x 2 K-steps.
  // B[k=quad*8+j][n=ntile*16+c] = We[k][h] = WeT[h][k] -> 8 contiguous bf16 = 16B.
  short8 Bf[8][2];
#pragma unroll
  for (int n = 0; n < 8; ++n)
#pragma unroll
    for (int ks = 0; ks < 2; ++ks)
      Bf[n][ks] = *(const short8*)&WeT[(n * 16 + c) * WTS_ + ks * 32 + quad * 8];

  float beL[8], wrL[8];
#pragma unroll
  for (int n = 0; n < 8; ++n) { beL[n] = be[n * 16 + c]; wrL[n] = Wr[n * 16 + c]; }
  const float brS = br[0];

  const int gw = blockIdx.x * 4 + wv;

  for (int it = 0; it < L_; ++it) {
    const int g = gw + it * NWAVE_;          // group of 4 consecutive windows

    // ---- A fragments: this lane supplies pixel p=c, channels quad*8..+7 (+32) ----
    const int w0   = g * 4 + (c >> 2);       // window of pixel p=c
    const int elem = c & 3;                  // elem = si*2+sj
    const int bb = w0 >> 12;                 // / (SR*SC)
    const int qq = (w0 >> 6) & 63;
    const int pp = w0 & 63;
    const int row = qq * 2 + (elem >> 1);
    const int col = pp * 2 + (elem & 1);
    const float* xp = x + (((bb * R_ + row) * C_ + col) * D_) + quad * 8;
    floatx4 a0 = *(const floatx4*)(xp);
    floatx4 a1 = *(const floatx4*)(xp + 4);
    floatx4 a2 = *(const floatx4*)(xp + 32);
    floatx4 a3 = *(const floatx4*)(xp + 36);

    short8 A0, A1;
    A0[0] = (short)f2bf(a0[0]); A0[1] = (short)f2bf(a0[1]);
    A0[2] = (short)f2bf(a0[2]); A0[3] = (short)f2bf(a0[3]);
    A0[4] = (short)f2bf(a1[0]); A0[5] = (short)f2bf(a1[1]);
    A0[6] = (short)f2bf(a1[2]); A0[7] = (short)f2bf(a1[3]);
    A1[0] = (short)f2bf(a2[0]); A1[1] = (short)f2bf(a2[1]);
    A1[2] = (short)f2bf(a2[2]); A1[3] = (short)f2bf(a2[3]);
    A1[4] = (short)f2bf(a3[0]); A1[5] = (short)f2bf(a3[1]);
    A1[6] = (short)f2bf(a3[2]); A1[7] = (short)f2bf(a3[3]);

    // ---- 16 MFMAs: h for 16 pixels x 128 hidden ----
    floatx4 acc[8];
#pragma unroll
    for (int n = 0; n < 8; ++n) {
      floatx4 z = {0.f, 0.f, 0.f, 0.f};
      z = __builtin_amdgcn_mfma_f32_16x16x32_bf16(A0, Bf[n][0], z, 0, 0, 0);
      acc[n] = __builtin_amdgcn_mfma_f32_16x16x32_bf16(A1, Bf[n][1], z, 0, 0, 0);
    }

    // ---- tanh + dot with Wr: per-lane partials over cols h = n*16 + c ----
    float p0 = 0.f, p1 = 0.f, p2 = 0.f, p3 = 0.f;
#pragma unroll
    for (int n = 0; n < 8; ++n) {
      p0 += fast_tanh(acc[n][0] + beL[n]) * wrL[n];
      p1 += fast_tanh(acc[n][1] + beL[n]) * wrL[n];
      p2 += fast_tanh(acc[n][2] + beL[n]) * wrL[n];
      p3 += fast_tanh(acc[n][3] + beL[n]) * wrL[n];
    }
    // reduce over the 16 lanes of this quad (cols c=0..15)
#pragma unroll
    for (int m = 1; m < 16; m <<= 1) {
      p0 += __shfl_xor(p0, m, 64);
      p1 += __shfl_xor(p1, m, 64);
      p2 += __shfl_xor(p2, m, 64);
      p3 += __shfl_xor(p3, m, 64);
    }
    // lane now holds the 4 logit-preacts of window (g*4 + quad), elems 0..3 (reg r = elem r)
    float l0 = 1.0f / (1.0f + __expf(-(p0 + brS)));
    float l1 = 1.0f / (1.0f + __expf(-(p1 + brS)));
    float l2 = 1.0f / (1.0f + __expf(-(p2 + brS)));
    float l3 = 1.0f / (1.0f + __expf(-(p3 + brS)));
    float mx = fmaxf(fmaxf(l0, l1), fmaxf(l2, l3));
    float e0 = __expf(l0 - mx), e1 = __expf(l1 - mx);
    float e2 = __expf(l2 - mx), e3 = __expf(l3 - mx);
    float inv = 1.0f / (e0 + e1 + e2 + e3);
    float w0f = e0 * inv, w1f = e1 * inv, w2f = e2 * inv, w3f = e3 * inv;

    // ---- fp32 blend: window wq = g*4 + quad, this lane does channels c*4..c*4+3 ----
    const int wq = g * 4 + quad;
    const int b2 = wq >> 12;
    const int q2 = (wq >> 6) & 63;
    const int p2i = wq & 63;
    const float* xw = x + (((b2 * R_ + q2 * 2) * C_ + p2i * 2) * D_) + c * 4;
    floatx4 x0 = *(const floatx4*)(xw);                 // elem0: (+0,+0)
    floatx4 x1 = *(const floatx4*)(xw + D_);            // elem1: (+0,+1)
    floatx4 x2 = *(const floatx4*)(xw + C_ * D_);       // elem2: (+1,+0)
    floatx4 x3 = *(const floatx4*)(xw + C_ * D_ + D_);  // elem3: (+1,+1)
    floatx4 o = x0 * w0f + x1 * w1f + x2 * w2f + x3 * w3f;
    *(floatx4*)(out + wq * 64 + c * 4) = o;             // wave writes 1KiB contiguous
  }
}

extern "C" void kernel_launch(void* const* d_in, const int* in_sizes, int n_in,
                              void* d_out, int out_size, void* d_ws, size_t ws_size,
                              hipStream_t stream) {
  const float* x  = (const float*)d_in[0];
  const float* We = (const float*)d_in[1];
  const float* be = (const float*)d_in[2];
  const float* Wr = (const float*)d_in[3];
  const float* br = (const float*)d_in[4];
  float* out = (float*)d_out;
  softpool_kernel<<<NBLK_, 256, 0, stream>>>(x, We, be, Wr, br, out);
}